// Round 1
// baseline (1864.924 us; speedup 1.0000x reference)
//
#include <hip/hip_runtime.h>

namespace {

constexpr int NCOMP = 48;
constexpr int RESN  = 300;
constexpr int NFEAT = 27;
constexpr int NPTS  = 1000000;
constexpr int CCTOT = 3 * NCOMP;   // 144

// ---------------- layout-transform kernels (run every call; d_ws is re-poisoned) ----

// planes (3,48,300,300) -> planes_t (3,300,300,48): channel-contiguous corners
__global__ void transpose_planes_k(const float* __restrict__ src,
                                   float* __restrict__ dst) {
    int idx = blockIdx.x * blockDim.x + threadIdx.x;
    constexpr int total = 3 * RESN * RESN;
    if (idx >= total) return;
    int i   = idx / (RESN * RESN);
    int rem = idx - i * (RESN * RESN);          // y*RESN + x
    const float* s = src + (size_t)i * NCOMP * RESN * RESN + rem;
    float* d = dst + (size_t)idx * NCOMP;
#pragma unroll
    for (int c = 0; c < NCOMP; ++c)
        d[c] = s[(size_t)c * RESN * RESN];      // reads coalesced across lanes (x-contig)
}

// lines (3,48,300,1) -> lines_t (3,300,48)
__global__ void transpose_lines_k(const float* __restrict__ src,
                                  float* __restrict__ dst) {
    int idx = blockIdx.x * blockDim.x + threadIdx.x;
    constexpr int total = 3 * RESN;
    if (idx >= total) return;
    int i = idx / RESN;
    int y = idx - i * RESN;
    const float* s = src + (size_t)i * NCOMP * RESN + y;
    float* d = dst + (size_t)idx * NCOMP;
#pragma unroll
    for (int c = 0; c < NCOMP; ++c)
        d[c] = s[(size_t)c * RESN];
}

// basis_W (27,144) -> Wt (144,27): f-contiguous rows for uniform scalar loads
__global__ void transpose_w_k(const float* __restrict__ src,
                              float* __restrict__ dst) {
    int idx = blockIdx.x * blockDim.x + threadIdx.x;
    constexpr int total = NFEAT * CCTOT;
    if (idx >= total) return;
    int f  = idx / CCTOT;
    int cc = idx - f * CCTOT;
    dst[(size_t)cc * NFEAT + f] = src[idx];
}

// ---------------- main fused kernel ----------------

__device__ __forceinline__ void accum_mode(float gx, float gy, float gl,
                                           const float* __restrict__ pt_i,
                                           const float* __restrict__ lt_i,
                                           const float* __restrict__ wt_i,
                                           float* __restrict__ acc) {
    float x = (gx + 1.0f) * 0.5f * (float)(RESN - 1);
    float y = (gy + 1.0f) * 0.5f * (float)(RESN - 1);
    float l = (gl + 1.0f) * 0.5f * (float)(RESN - 1);
    float x0f = floorf(x), y0f = floorf(y), l0f = floorf(l);
    float wx = x - x0f, wy = y - y0f, wl = l - l0f;
    int x0 = (int)x0f; x0 = max(0, min(x0, RESN - 1));
    int y0 = (int)y0f; y0 = max(0, min(y0, RESN - 1));
    int l0 = (int)l0f; l0 = max(0, min(l0, RESN - 1));
    int x1 = min(x0 + 1, RESN - 1);
    int y1 = min(y0 + 1, RESN - 1);
    int l1 = min(l0 + 1, RESN - 1);
    float w00 = (1.0f - wy) * (1.0f - wx);
    float w01 = (1.0f - wy) * wx;
    float w10 = wy * (1.0f - wx);
    float w11 = wy * wx;
    float wl0 = 1.0f - wl;
    float wl1 = wl;

    const float4* p00 = (const float4*)(pt_i + ((size_t)y0 * RESN + x0) * NCOMP);
    const float4* p01 = (const float4*)(pt_i + ((size_t)y0 * RESN + x1) * NCOMP);
    const float4* p10 = (const float4*)(pt_i + ((size_t)y1 * RESN + x0) * NCOMP);
    const float4* p11 = (const float4*)(pt_i + ((size_t)y1 * RESN + x1) * NCOMP);
    const float4* L0  = (const float4*)(lt_i + (size_t)l0 * NCOMP);
    const float4* L1  = (const float4*)(lt_i + (size_t)l1 * NCOMP);

#pragma unroll 2
    for (int g = 0; g < NCOMP / 4; ++g) {
        float4 a = p00[g], b = p01[g], c = p10[g], d = p11[g];
        float4 e0 = L0[g], e1 = L1[g];
        float prx = (w00*a.x + w01*b.x + w10*c.x + w11*d.x) * (wl0*e0.x + wl1*e1.x);
        float pry = (w00*a.y + w01*b.y + w10*c.y + w11*d.y) * (wl0*e0.y + wl1*e1.y);
        float prz = (w00*a.z + w01*b.z + w10*c.z + w11*d.z) * (wl0*e0.z + wl1*e1.z);
        float prw = (w00*a.w + w01*b.w + w10*c.w + w11*d.w) * (wl0*e0.w + wl1*e1.w);
        // wave-uniform addresses -> scalar loads, shared by all 64 lanes
        const float* w0 = wt_i + (size_t)(4*g + 0) * NFEAT;
        const float* w1 = wt_i + (size_t)(4*g + 1) * NFEAT;
        const float* w2 = wt_i + (size_t)(4*g + 2) * NFEAT;
        const float* w3 = wt_i + (size_t)(4*g + 3) * NFEAT;
#pragma unroll
        for (int f = 0; f < NFEAT; ++f) {
            acc[f] += prx * w0[f] + pry * w1[f] + prz * w2[f] + prw * w3[f];
        }
    }
}

__global__ __launch_bounds__(256) void tensor_vm_kernel(
    const float* __restrict__ xyz,
    const float* __restrict__ pt,
    const float* __restrict__ lt,
    const float* __restrict__ wt,
    float* __restrict__ out) {
    int p = blockIdx.x * blockDim.x + threadIdx.x;
    if (p >= NPTS) return;
    float q0 = xyz[3 * (size_t)p + 0];
    float q1 = xyz[3 * (size_t)p + 1];
    float q2 = xyz[3 * (size_t)p + 2];
    float acc[NFEAT];
#pragma unroll
    for (int f = 0; f < NFEAT; ++f) acc[f] = 0.0f;

    constexpr size_t PSZ = (size_t)RESN * RESN * NCOMP;
    constexpr size_t LSZ = (size_t)RESN * NCOMP;
    constexpr int    WSZ = NCOMP * NFEAT;

    // PLANE_AX = ((2,1),(2,0),(1,0)); line axis = mode index
    accum_mode(q2, q1, q0, pt,           lt,           wt,           acc);
    accum_mode(q2, q0, q1, pt + PSZ,     lt + LSZ,     wt + WSZ,     acc);
    accum_mode(q1, q0, q2, pt + 2 * PSZ, lt + 2 * LSZ, wt + 2 * WSZ, acc);

    float* o = out + (size_t)p * NFEAT;
#pragma unroll
    for (int f = 0; f < NFEAT; ++f) o[f] = acc[f];
}

// ---------------- fallback (original layouts) if d_ws is too small ----------------

__global__ __launch_bounds__(256) void tensor_vm_naive_kernel(
    const float* __restrict__ xyz,
    const float* __restrict__ planes,
    const float* __restrict__ lines,
    const float* __restrict__ W,
    float* __restrict__ out) {
    int p = blockIdx.x * blockDim.x + threadIdx.x;
    if (p >= NPTS) return;
    float q[3];
    q[0] = xyz[3 * (size_t)p + 0];
    q[1] = xyz[3 * (size_t)p + 1];
    q[2] = xyz[3 * (size_t)p + 2];
    float acc[NFEAT];
    for (int f = 0; f < NFEAT; ++f) acc[f] = 0.0f;
    const int AX[3] = {2, 2, 1};
    const int BX[3] = {1, 0, 0};
    for (int i = 0; i < 3; ++i) {
        float gx = q[AX[i]], gy = q[BX[i]], gl = q[i];
        float x = (gx + 1.0f) * 0.5f * (float)(RESN - 1);
        float y = (gy + 1.0f) * 0.5f * (float)(RESN - 1);
        float l = (gl + 1.0f) * 0.5f * (float)(RESN - 1);
        float x0f = floorf(x), y0f = floorf(y), l0f = floorf(l);
        float wx = x - x0f, wy = y - y0f, wl = l - l0f;
        int x0 = max(0, min((int)x0f, RESN - 1));
        int y0 = max(0, min((int)y0f, RESN - 1));
        int l0 = max(0, min((int)l0f, RESN - 1));
        int x1 = min(x0 + 1, RESN - 1);
        int y1 = min(y0 + 1, RESN - 1);
        int l1 = min(l0 + 1, RESN - 1);
        float w00 = (1.0f - wy) * (1.0f - wx);
        float w01 = (1.0f - wy) * wx;
        float w10 = wy * (1.0f - wx);
        float w11 = wy * wx;
        const float* pl = planes + (size_t)i * NCOMP * RESN * RESN;
        const float* ln = lines + (size_t)i * NCOMP * RESN;
        for (int c = 0; c < NCOMP; ++c) {
            const float* plc = pl + (size_t)c * RESN * RESN;
            float v00 = plc[(size_t)y0 * RESN + x0];
            float v01 = plc[(size_t)y0 * RESN + x1];
            float v10 = plc[(size_t)y1 * RESN + x0];
            float v11 = plc[(size_t)y1 * RESN + x1];
            float pv = w00 * v00 + w01 * v01 + w10 * v10 + w11 * v11;
            float lv = (1.0f - wl) * ln[(size_t)c * RESN + l0] + wl * ln[(size_t)c * RESN + l1];
            float pr = pv * lv;
            int cc = i * NCOMP + c;
            for (int f = 0; f < NFEAT; ++f)
                acc[f] += pr * W[(size_t)f * CCTOT + cc];
        }
    }
    float* o = out + (size_t)p * NFEAT;
    for (int f = 0; f < NFEAT; ++f) o[f] = acc[f];
}

}  // namespace

extern "C" void kernel_launch(void* const* d_in, const int* in_sizes, int n_in,
                              void* d_out, int out_size, void* d_ws, size_t ws_size,
                              hipStream_t stream) {
    (void)in_sizes; (void)n_in; (void)out_size;
    const float* xyz    = (const float*)d_in[0];
    const float* planes = (const float*)d_in[1];
    const float* lines  = (const float*)d_in[2];
    const float* W      = (const float*)d_in[3];
    float* out = (float*)d_out;

    constexpr size_t PT_FLOATS = (size_t)3 * RESN * RESN * NCOMP;  // 12,960,000
    constexpr size_t LT_FLOATS = (size_t)3 * RESN * NCOMP;         // 43,200
    constexpr size_t WT_FLOATS = (size_t)CCTOT * NFEAT;            // 3,888
    constexpr size_t NEED = (PT_FLOATS + LT_FLOATS + WT_FLOATS) * sizeof(float);

    if (ws_size >= NEED) {
        float* pt = (float*)d_ws;
        float* lt = pt + PT_FLOATS;
        float* wt = lt + LT_FLOATS;
        {
            constexpr int total = 3 * RESN * RESN;
            transpose_planes_k<<<(total + 255) / 256, 256, 0, stream>>>(planes, pt);
        }
        {
            constexpr int total = 3 * RESN;
            transpose_lines_k<<<(total + 255) / 256, 256, 0, stream>>>(lines, lt);
        }
        {
            constexpr int total = NFEAT * CCTOT;
            transpose_w_k<<<(total + 255) / 256, 256, 0, stream>>>(W, wt);
        }
        tensor_vm_kernel<<<(NPTS + 255) / 256, 256, 0, stream>>>(xyz, pt, lt, wt, out);
    } else {
        tensor_vm_naive_kernel<<<(NPTS + 255) / 256, 256, 0, stream>>>(xyz, planes, lines, W, out);
    }
}

// Round 2
// 575.670 us; speedup vs baseline: 3.2396x; 3.2396x over previous
//
#include <hip/hip_runtime.h>

namespace {

constexpr int NCOMP = 48;
constexpr int RESN  = 300;
constexpr int NFEAT = 27;
constexpr int NPTS  = 1000000;
constexpr int CCTOT = 3 * NCOMP;   // 144

typedef _Float16 half_t;
typedef __attribute__((ext_vector_type(8))) _Float16 half8;

// ---------------- layout-transform kernels (run every call; d_ws is re-poisoned) ----

// planes (3,48,300,300) fp32 -> planes_t (3,300,300,48) fp16
__global__ void transpose_planes_k(const float* __restrict__ src,
                                   half_t* __restrict__ dst) {
    int idx = blockIdx.x * blockDim.x + threadIdx.x;
    constexpr int total = 3 * RESN * RESN;
    if (idx >= total) return;
    int i   = idx / (RESN * RESN);
    int rem = idx - i * (RESN * RESN);          // y*RESN + x
    const float* s = src + (size_t)i * NCOMP * RESN * RESN + rem;
    half8* d = (half8*)(dst + (size_t)idx * NCOMP);
#pragma unroll
    for (int g = 0; g < NCOMP / 8; ++g) {
        half8 h;
#pragma unroll
        for (int k = 0; k < 8; ++k)
            h[k] = (half_t)s[(size_t)(g * 8 + k) * (RESN * RESN)];  // coalesced across lanes
        d[g] = h;
    }
}

// lines (3,48,300,1) fp32 -> lines_t (3,300,48) fp16
__global__ void transpose_lines_k(const float* __restrict__ src,
                                  half_t* __restrict__ dst) {
    int idx = blockIdx.x * blockDim.x + threadIdx.x;
    constexpr int total = 3 * RESN;
    if (idx >= total) return;
    int i = idx / RESN;
    int y = idx - i * RESN;
    const float* s = src + (size_t)i * NCOMP * RESN + y;
    half8* d = (half8*)(dst + (size_t)idx * NCOMP);
#pragma unroll
    for (int g = 0; g < NCOMP / 8; ++g) {
        half8 h;
#pragma unroll
        for (int k = 0; k < 8; ++k)
            h[k] = (half_t)s[(size_t)(g * 8 + k) * RESN];
        d[g] = h;
    }
}

// basis_W (27,144) -> Wt (144,27): f-contiguous rows for uniform scalar loads
__global__ void transpose_w_k(const float* __restrict__ src,
                              float* __restrict__ dst) {
    int idx = blockIdx.x * blockDim.x + threadIdx.x;
    constexpr int total = NFEAT * CCTOT;
    if (idx >= total) return;
    int f  = idx / CCTOT;
    int cc = idx - f * CCTOT;
    dst[(size_t)cc * NFEAT + f] = src[idx];
}

// ---------------- main fused kernel ----------------

__device__ __forceinline__ void accum_mode(float gx, float gy, float gl,
                                           const half_t* __restrict__ pt_i,
                                           const half_t* __restrict__ lt_i,
                                           const float* __restrict__ wt_i,
                                           float* __restrict__ acc) {
    float x = (gx + 1.0f) * 0.5f * (float)(RESN - 1);
    float y = (gy + 1.0f) * 0.5f * (float)(RESN - 1);
    float l = (gl + 1.0f) * 0.5f * (float)(RESN - 1);
    float x0f = floorf(x), y0f = floorf(y), l0f = floorf(l);
    float wx = x - x0f, wy = y - y0f, wl = l - l0f;
    int x0 = (int)x0f; x0 = max(0, min(x0, RESN - 1));
    int y0 = (int)y0f; y0 = max(0, min(y0, RESN - 1));
    int l0 = (int)l0f; l0 = max(0, min(l0, RESN - 1));
    int x1 = min(x0 + 1, RESN - 1);
    int y1 = min(y0 + 1, RESN - 1);
    int l1 = min(l0 + 1, RESN - 1);
    float w00 = (1.0f - wy) * (1.0f - wx);
    float w01 = (1.0f - wy) * wx;
    float w10 = wy * (1.0f - wx);
    float w11 = wy * wx;
    float wl0 = 1.0f - wl;
    float wl1 = wl;

    const half8* p00 = (const half8*)(pt_i + ((size_t)y0 * RESN + x0) * NCOMP);
    const half8* p01 = (const half8*)(pt_i + ((size_t)y0 * RESN + x1) * NCOMP);
    const half8* p10 = (const half8*)(pt_i + ((size_t)y1 * RESN + x0) * NCOMP);
    const half8* p11 = (const half8*)(pt_i + ((size_t)y1 * RESN + x1) * NCOMP);
    const half8* L0  = (const half8*)(lt_i + (size_t)l0 * NCOMP);
    const half8* L1  = (const half8*)(lt_i + (size_t)l1 * NCOMP);

#pragma unroll 2
    for (int g = 0; g < NCOMP / 8; ++g) {
        half8 a = p00[g], b = p01[g], c = p10[g], d = p11[g];
        half8 e0 = L0[g], e1 = L1[g];
#pragma unroll
        for (int j = 0; j < 8; ++j) {
            float pv = w00 * (float)a[j] + w01 * (float)b[j]
                     + w10 * (float)c[j] + w11 * (float)d[j];
            float lv = wl0 * (float)e0[j] + wl1 * (float)e1[j];
            float pr = pv * lv;
            // wave-uniform addresses -> scalar loads, shared by all 64 lanes
            const float* wrow = wt_i + (size_t)(8 * g + j) * NFEAT;
#pragma unroll
            for (int f = 0; f < NFEAT; ++f)
                acc[f] += pr * wrow[f];
        }
    }
}

__global__ __launch_bounds__(256) void tensor_vm_kernel(
    const float* __restrict__ xyz,
    const half_t* __restrict__ pt,
    const half_t* __restrict__ lt,
    const float* __restrict__ wt,
    float* __restrict__ out) {
    int p = blockIdx.x * blockDim.x + threadIdx.x;
    if (p >= NPTS) return;
    float q0 = xyz[3 * (size_t)p + 0];
    float q1 = xyz[3 * (size_t)p + 1];
    float q2 = xyz[3 * (size_t)p + 2];
    float acc[NFEAT];
#pragma unroll
    for (int f = 0; f < NFEAT; ++f) acc[f] = 0.0f;

    constexpr size_t PSZ = (size_t)RESN * RESN * NCOMP;
    constexpr size_t LSZ = (size_t)RESN * NCOMP;
    constexpr int    WSZ = NCOMP * NFEAT;

    // PLANE_AX = ((2,1),(2,0),(1,0)); line axis = mode index
    accum_mode(q2, q1, q0, pt,           lt,           wt,           acc);
    accum_mode(q2, q0, q1, pt + PSZ,     lt + LSZ,     wt + WSZ,     acc);
    accum_mode(q1, q0, q2, pt + 2 * PSZ, lt + 2 * LSZ, wt + 2 * WSZ, acc);

    float* o = out + (size_t)p * NFEAT;
#pragma unroll
    for (int f = 0; f < NFEAT; ++f) o[f] = acc[f];
}

// ---------------- fallback (original layouts) if d_ws is too small ----------------

__global__ __launch_bounds__(256) void tensor_vm_naive_kernel(
    const float* __restrict__ xyz,
    const float* __restrict__ planes,
    const float* __restrict__ lines,
    const float* __restrict__ W,
    float* __restrict__ out) {
    int p = blockIdx.x * blockDim.x + threadIdx.x;
    if (p >= NPTS) return;
    float q[3];
    q[0] = xyz[3 * (size_t)p + 0];
    q[1] = xyz[3 * (size_t)p + 1];
    q[2] = xyz[3 * (size_t)p + 2];
    float acc[NFEAT];
    for (int f = 0; f < NFEAT; ++f) acc[f] = 0.0f;
    const int AX[3] = {2, 2, 1};
    const int BX[3] = {1, 0, 0};
    for (int i = 0; i < 3; ++i) {
        float gx = q[AX[i]], gy = q[BX[i]], gl = q[i];
        float x = (gx + 1.0f) * 0.5f * (float)(RESN - 1);
        float y = (gy + 1.0f) * 0.5f * (float)(RESN - 1);
        float l = (gl + 1.0f) * 0.5f * (float)(RESN - 1);
        float x0f = floorf(x), y0f = floorf(y), l0f = floorf(l);
        float wx = x - x0f, wy = y - y0f, wl = l - l0f;
        int x0 = max(0, min((int)x0f, RESN - 1));
        int y0 = max(0, min((int)y0f, RESN - 1));
        int l0 = max(0, min((int)l0f, RESN - 1));
        int x1 = min(x0 + 1, RESN - 1);
        int y1 = min(y0 + 1, RESN - 1);
        int l1 = min(l0 + 1, RESN - 1);
        float w00 = (1.0f - wy) * (1.0f - wx);
        float w01 = (1.0f - wy) * wx;
        float w10 = wy * (1.0f - wx);
        float w11 = wy * wx;
        const float* pl = planes + (size_t)i * NCOMP * RESN * RESN;
        const float* ln = lines + (size_t)i * NCOMP * RESN;
        for (int c = 0; c < NCOMP; ++c) {
            const float* plc = pl + (size_t)c * RESN * RESN;
            float v00 = plc[(size_t)y0 * RESN + x0];
            float v01 = plc[(size_t)y0 * RESN + x1];
            float v10 = plc[(size_t)y1 * RESN + x0];
            float v11 = plc[(size_t)y1 * RESN + x1];
            float pv = w00 * v00 + w01 * v01 + w10 * v10 + w11 * v11;
            float lv = (1.0f - wl) * ln[(size_t)c * RESN + l0] + wl * ln[(size_t)c * RESN + l1];
            float pr = pv * lv;
            int cc = i * NCOMP + c;
            for (int f = 0; f < NFEAT; ++f)
                acc[f] += pr * W[(size_t)f * CCTOT + cc];
        }
    }
    float* o = out + (size_t)p * NFEAT;
    for (int f = 0; f < NFEAT; ++f) o[f] = acc[f];
}

}  // namespace

extern "C" void kernel_launch(void* const* d_in, const int* in_sizes, int n_in,
                              void* d_out, int out_size, void* d_ws, size_t ws_size,
                              hipStream_t stream) {
    (void)in_sizes; (void)n_in; (void)out_size;
    const float* xyz    = (const float*)d_in[0];
    const float* planes = (const float*)d_in[1];
    const float* lines  = (const float*)d_in[2];
    const float* W      = (const float*)d_in[3];
    float* out = (float*)d_out;

    constexpr size_t PT_HALVES = (size_t)3 * RESN * RESN * NCOMP;  // 12,960,000
    constexpr size_t LT_HALVES = (size_t)3 * RESN * NCOMP;         // 43,200
    constexpr size_t WT_FLOATS = (size_t)CCTOT * NFEAT;            // 3,888
    // layout in d_ws: [wt fp32][pt fp16][lt fp16]
    constexpr size_t WT_BYTES = WT_FLOATS * sizeof(float);         // 15,552 (16B-mult)
    constexpr size_t NEED = WT_BYTES + (PT_HALVES + LT_HALVES) * sizeof(half_t);

    if (ws_size >= NEED) {
        float*  wt = (float*)d_ws;
        half_t* pt = (half_t*)((char*)d_ws + WT_BYTES);
        half_t* lt = pt + PT_HALVES;
        {
            constexpr int total = 3 * RESN * RESN;
            transpose_planes_k<<<(total + 255) / 256, 256, 0, stream>>>(planes, pt);
        }
        {
            constexpr int total = 3 * RESN;
            transpose_lines_k<<<(total + 255) / 256, 256, 0, stream>>>(lines, lt);
        }
        {
            constexpr int total = NFEAT * CCTOT;
            transpose_w_k<<<(total + 255) / 256, 256, 0, stream>>>(W, wt);
        }
        tensor_vm_kernel<<<(NPTS + 255) / 256, 256, 0, stream>>>(xyz, pt, lt, wt, out);
    } else {
        tensor_vm_naive_kernel<<<(NPTS + 255) / 256, 256, 0, stream>>>(xyz, planes, lines, W, out);
    }
}

// Round 3
// 492.139 us; speedup vs baseline: 3.7894x; 1.1697x over previous
//
#include <hip/hip_runtime.h>

namespace {

constexpr int NCOMP = 48;
constexpr int RESN  = 300;
constexpr int NFEAT = 27;
constexpr int NPTS  = 1000000;
constexpr int CCTOT = 3 * NCOMP;   // 144
constexpr int GRID1 = 32;          // sort cells per axis
constexpr int NBUCKET = GRID1 * GRID1 * GRID1;  // 32768

typedef _Float16 half_t;
typedef __attribute__((ext_vector_type(8))) _Float16 half8;

// ---------------- layout-transform kernels ----------------

// planes (3,48,300,300) fp32 -> planes_t (3,300,300,48) fp16
__global__ void transpose_planes_k(const float* __restrict__ src,
                                   half_t* __restrict__ dst) {
    int idx = blockIdx.x * blockDim.x + threadIdx.x;
    constexpr int total = 3 * RESN * RESN;
    if (idx >= total) return;
    int i   = idx / (RESN * RESN);
    int rem = idx - i * (RESN * RESN);          // y*RESN + x
    const float* s = src + (size_t)i * NCOMP * RESN * RESN + rem;
    half8* d = (half8*)(dst + (size_t)idx * NCOMP);
#pragma unroll
    for (int g = 0; g < NCOMP / 8; ++g) {
        half8 h;
#pragma unroll
        for (int k = 0; k < 8; ++k)
            h[k] = (half_t)s[(size_t)(g * 8 + k) * (RESN * RESN)];  // coalesced across lanes
        d[g] = h;
    }
}

// lines (3,48,300,1) fp32 -> lines_t (3,300,48) fp16
__global__ void transpose_lines_k(const float* __restrict__ src,
                                  half_t* __restrict__ dst) {
    int idx = blockIdx.x * blockDim.x + threadIdx.x;
    constexpr int total = 3 * RESN;
    if (idx >= total) return;
    int i = idx / RESN;
    int y = idx - i * RESN;
    const float* s = src + (size_t)i * NCOMP * RESN + y;
    half8* d = (half8*)(dst + (size_t)idx * NCOMP);
#pragma unroll
    for (int g = 0; g < NCOMP / 8; ++g) {
        half8 h;
#pragma unroll
        for (int k = 0; k < 8; ++k)
            h[k] = (half_t)s[(size_t)(g * 8 + k) * RESN];
        d[g] = h;
    }
}

// basis_W (27,144) -> Wt (144,27)
__global__ void transpose_w_k(const float* __restrict__ src,
                              float* __restrict__ dst) {
    int idx = blockIdx.x * blockDim.x + threadIdx.x;
    constexpr int total = NFEAT * CCTOT;
    if (idx >= total) return;
    int f  = idx / CCTOT;
    int cc = idx - f * CCTOT;
    dst[(size_t)cc * NFEAT + f] = src[idx];
}

// ---------------- counting sort by spatial cell ----------------

__device__ __forceinline__ int cell_of(float q) {
    float t = (q + 1.0f) * (0.5f * (float)GRID1);   // [0,32)
    int c = (int)t;
    return min(max(c, 0), GRID1 - 1);
}
// q2 fastest (plane col for modes 0,1), then q1 (plane col for mode 2)
__device__ __forceinline__ int key_of(float q0, float q1, float q2) {
    return (cell_of(q0) * GRID1 + cell_of(q1)) * GRID1 + cell_of(q2);
}

__global__ void zero_hist_k(int* __restrict__ hist) {
    int i = blockIdx.x * blockDim.x + threadIdx.x;
    if (i < NBUCKET) hist[i] = 0;
}

__global__ __launch_bounds__(256) void hist_k(const float* __restrict__ xyz,
                                              int* __restrict__ hist) {
    int p = blockIdx.x * blockDim.x + threadIdx.x;
    if (p >= NPTS) return;
    float q0 = xyz[3 * (size_t)p + 0];
    float q1 = xyz[3 * (size_t)p + 1];
    float q2 = xyz[3 * (size_t)p + 2];
    atomicAdd(&hist[key_of(q0, q1, q2)], 1);
}

// single-block exclusive scan of NBUCKET=32768 ints (1024 thr x 32 each)
__global__ __launch_bounds__(1024) void scan_k(const int* __restrict__ hist,
                                               int* __restrict__ start) {
    __shared__ int part[1024];
    int t = threadIdx.x;
    int base = t * (NBUCKET / 1024);
    int s = 0;
#pragma unroll 4
    for (int j = 0; j < NBUCKET / 1024; ++j) s += hist[base + j];
    part[t] = s;
    __syncthreads();
    for (int off = 1; off < 1024; off <<= 1) {
        int v = (t >= off) ? part[t - off] : 0;
        __syncthreads();
        part[t] += v;
        __syncthreads();
    }
    int run = (t == 0) ? 0 : part[t - 1];   // exclusive prefix of this thread's chunk
    for (int j = 0; j < NBUCKET / 1024; ++j) {
        start[base + j] = run;
        run += hist[base + j];
    }
}

// scatter: pack {x,y,z,perm-as-float} into one aligned float4 per sorted slot
__global__ __launch_bounds__(256) void scatter_k(const float* __restrict__ xyz,
                                                 int* __restrict__ start,
                                                 float4* __restrict__ xyzs) {
    int p = blockIdx.x * blockDim.x + threadIdx.x;
    if (p >= NPTS) return;
    float q0 = xyz[3 * (size_t)p + 0];
    float q1 = xyz[3 * (size_t)p + 1];
    float q2 = xyz[3 * (size_t)p + 2];
    int slot = atomicAdd(&start[key_of(q0, q1, q2)], 1);
    float4 v;
    v.x = q0; v.y = q1; v.z = q2; v.w = __int_as_float(p);
    xyzs[slot] = v;
}

// ---------------- main fused kernel ----------------

__device__ __forceinline__ void accum_mode(float gx, float gy, float gl,
                                           const half_t* __restrict__ pt_i,
                                           const half_t* __restrict__ lt_i,
                                           const float* __restrict__ wt_i,
                                           float* __restrict__ acc) {
    float x = (gx + 1.0f) * 0.5f * (float)(RESN - 1);
    float y = (gy + 1.0f) * 0.5f * (float)(RESN - 1);
    float l = (gl + 1.0f) * 0.5f * (float)(RESN - 1);
    float x0f = floorf(x), y0f = floorf(y), l0f = floorf(l);
    float wx = x - x0f, wy = y - y0f, wl = l - l0f;
    int x0 = (int)x0f; x0 = max(0, min(x0, RESN - 1));
    int y0 = (int)y0f; y0 = max(0, min(y0, RESN - 1));
    int l0 = (int)l0f; l0 = max(0, min(l0, RESN - 1));
    int x1 = min(x0 + 1, RESN - 1);
    int y1 = min(y0 + 1, RESN - 1);
    int l1 = min(l0 + 1, RESN - 1);
    float w00 = (1.0f - wy) * (1.0f - wx);
    float w01 = (1.0f - wy) * wx;
    float w10 = wy * (1.0f - wx);
    float w11 = wy * wx;
    float wl0 = 1.0f - wl;
    float wl1 = wl;

    const half8* p00 = (const half8*)(pt_i + ((size_t)y0 * RESN + x0) * NCOMP);
    const half8* p01 = (const half8*)(pt_i + ((size_t)y0 * RESN + x1) * NCOMP);
    const half8* p10 = (const half8*)(pt_i + ((size_t)y1 * RESN + x0) * NCOMP);
    const half8* p11 = (const half8*)(pt_i + ((size_t)y1 * RESN + x1) * NCOMP);
    const half8* L0  = (const half8*)(lt_i + (size_t)l0 * NCOMP);
    const half8* L1  = (const half8*)(lt_i + (size_t)l1 * NCOMP);

#pragma unroll 2
    for (int g = 0; g < NCOMP / 8; ++g) {
        half8 a = p00[g], b = p01[g], c = p10[g], d = p11[g];
        half8 e0 = L0[g], e1 = L1[g];
#pragma unroll
        for (int j = 0; j < 8; ++j) {
            float pv = w00 * (float)a[j] + w01 * (float)b[j]
                     + w10 * (float)c[j] + w11 * (float)d[j];
            float lv = wl0 * (float)e0[j] + wl1 * (float)e1[j];
            float pr = pv * lv;
            const float* wrow = wt_i + (size_t)(8 * g + j) * NFEAT;  // wave-uniform
#pragma unroll
            for (int f = 0; f < NFEAT; ++f)
                acc[f] += pr * wrow[f];
        }
    }
}

__global__ __launch_bounds__(256) void tensor_vm_sorted_kernel(
    const float4* __restrict__ xyzs,
    const half_t* __restrict__ pt,
    const half_t* __restrict__ lt,
    const float* __restrict__ wt,
    float* __restrict__ out) {
    int i = blockIdx.x * blockDim.x + threadIdx.x;
    if (i >= NPTS) return;
    float4 v = xyzs[i];
    float q0 = v.x, q1 = v.y, q2 = v.z;
    int p = __float_as_int(v.w);
    float acc[NFEAT];
#pragma unroll
    for (int f = 0; f < NFEAT; ++f) acc[f] = 0.0f;

    constexpr size_t PSZ = (size_t)RESN * RESN * NCOMP;
    constexpr size_t LSZ = (size_t)RESN * NCOMP;
    constexpr int    WSZ = NCOMP * NFEAT;

    // PLANE_AX = ((2,1),(2,0),(1,0)); line axis = mode index
    accum_mode(q2, q1, q0, pt,           lt,           wt,           acc);
    accum_mode(q2, q0, q1, pt + PSZ,     lt + LSZ,     wt + WSZ,     acc);
    accum_mode(q1, q0, q2, pt + 2 * PSZ, lt + 2 * LSZ, wt + 2 * WSZ, acc);

    float* o = out + (size_t)p * NFEAT;
#pragma unroll
    for (int f = 0; f < NFEAT; ++f) o[f] = acc[f];
}

// unsorted variant (mid fallback)
__global__ __launch_bounds__(256) void tensor_vm_kernel(
    const float* __restrict__ xyz,
    const half_t* __restrict__ pt,
    const half_t* __restrict__ lt,
    const float* __restrict__ wt,
    float* __restrict__ out) {
    int p = blockIdx.x * blockDim.x + threadIdx.x;
    if (p >= NPTS) return;
    float q0 = xyz[3 * (size_t)p + 0];
    float q1 = xyz[3 * (size_t)p + 1];
    float q2 = xyz[3 * (size_t)p + 2];
    float acc[NFEAT];
#pragma unroll
    for (int f = 0; f < NFEAT; ++f) acc[f] = 0.0f;
    constexpr size_t PSZ = (size_t)RESN * RESN * NCOMP;
    constexpr size_t LSZ = (size_t)RESN * NCOMP;
    constexpr int    WSZ = NCOMP * NFEAT;
    accum_mode(q2, q1, q0, pt,           lt,           wt,           acc);
    accum_mode(q2, q0, q1, pt + PSZ,     lt + LSZ,     wt + WSZ,     acc);
    accum_mode(q1, q0, q2, pt + 2 * PSZ, lt + 2 * LSZ, wt + 2 * WSZ, acc);
    float* o = out + (size_t)p * NFEAT;
#pragma unroll
    for (int f = 0; f < NFEAT; ++f) o[f] = acc[f];
}

// ---------------- naive fallback (original layouts) ----------------

__global__ __launch_bounds__(256) void tensor_vm_naive_kernel(
    const float* __restrict__ xyz,
    const float* __restrict__ planes,
    const float* __restrict__ lines,
    const float* __restrict__ W,
    float* __restrict__ out) {
    int p = blockIdx.x * blockDim.x + threadIdx.x;
    if (p >= NPTS) return;
    float q[3];
    q[0] = xyz[3 * (size_t)p + 0];
    q[1] = xyz[3 * (size_t)p + 1];
    q[2] = xyz[3 * (size_t)p + 2];
    float acc[NFEAT];
    for (int f = 0; f < NFEAT; ++f) acc[f] = 0.0f;
    const int AX[3] = {2, 2, 1};
    const int BX[3] = {1, 0, 0};
    for (int i = 0; i < 3; ++i) {
        float gx = q[AX[i]], gy = q[BX[i]], gl = q[i];
        float x = (gx + 1.0f) * 0.5f * (float)(RESN - 1);
        float y = (gy + 1.0f) * 0.5f * (float)(RESN - 1);
        float l = (gl + 1.0f) * 0.5f * (float)(RESN - 1);
        float x0f = floorf(x), y0f = floorf(y), l0f = floorf(l);
        float wx = x - x0f, wy = y - y0f, wl = l - l0f;
        int x0 = max(0, min((int)x0f, RESN - 1));
        int y0 = max(0, min((int)y0f, RESN - 1));
        int l0 = max(0, min((int)l0f, RESN - 1));
        int x1 = min(x0 + 1, RESN - 1);
        int y1 = min(y0 + 1, RESN - 1);
        int l1 = min(l0 + 1, RESN - 1);
        float w00 = (1.0f - wy) * (1.0f - wx);
        float w01 = (1.0f - wy) * wx;
        float w10 = wy * (1.0f - wx);
        float w11 = wy * wx;
        const float* pl = planes + (size_t)i * NCOMP * RESN * RESN;
        const float* ln = lines + (size_t)i * NCOMP * RESN;
        for (int c = 0; c < NCOMP; ++c) {
            const float* plc = pl + (size_t)c * RESN * RESN;
            float v00 = plc[(size_t)y0 * RESN + x0];
            float v01 = plc[(size_t)y0 * RESN + x1];
            float v10 = plc[(size_t)y1 * RESN + x0];
            float v11 = plc[(size_t)y1 * RESN + x1];
            float pv = w00 * v00 + w01 * v01 + w10 * v10 + w11 * v11;
            float lv = (1.0f - wl) * ln[(size_t)c * RESN + l0] + wl * ln[(size_t)c * RESN + l1];
            float pr = pv * lv;
            int cc = i * NCOMP + c;
            for (int f = 0; f < NFEAT; ++f)
                acc[f] += pr * W[(size_t)f * CCTOT + cc];
        }
    }
    float* o = out + (size_t)p * NFEAT;
    for (int f = 0; f < NFEAT; ++f) o[f] = acc[f];
}

}  // namespace

extern "C" void kernel_launch(void* const* d_in, const int* in_sizes, int n_in,
                              void* d_out, int out_size, void* d_ws, size_t ws_size,
                              hipStream_t stream) {
    (void)in_sizes; (void)n_in; (void)out_size;
    const float* xyz    = (const float*)d_in[0];
    const float* planes = (const float*)d_in[1];
    const float* lines  = (const float*)d_in[2];
    const float* W      = (const float*)d_in[3];
    float* out = (float*)d_out;

    constexpr size_t PT_HALVES = (size_t)3 * RESN * RESN * NCOMP;  // 12,960,000
    constexpr size_t LT_HALVES = (size_t)3 * RESN * NCOMP;         // 43,200
    constexpr size_t WT_FLOATS = (size_t)CCTOT * NFEAT;            // 3,888

    // ws layout: [wt fp32][pt fp16][lt fp16][hist int][start int][xyzs float4]
    constexpr size_t WT_BYTES    = WT_FLOATS * sizeof(float);       // 15,552 (16B mult)
    constexpr size_t PT_BYTES    = PT_HALVES * sizeof(half_t);      // 25,920,000
    constexpr size_t LT_BYTES    = LT_HALVES * sizeof(half_t);      // 86,400
    constexpr size_t HIST_BYTES  = (size_t)NBUCKET * sizeof(int);   // 131,072
    constexpr size_t XYZS_BYTES  = (size_t)NPTS * sizeof(float4);   // 16,000,000
    constexpr size_t NEED_PLAIN  = WT_BYTES + PT_BYTES + LT_BYTES;
    constexpr size_t NEED_SORT   = NEED_PLAIN + 2 * HIST_BYTES + XYZS_BYTES;

    if (ws_size >= NEED_PLAIN) {
        float*  wt = (float*)d_ws;
        half_t* pt = (half_t*)((char*)d_ws + WT_BYTES);
        half_t* lt = (half_t*)((char*)d_ws + WT_BYTES + PT_BYTES);
        {
            constexpr int total = 3 * RESN * RESN;
            transpose_planes_k<<<(total + 255) / 256, 256, 0, stream>>>(planes, pt);
        }
        {
            constexpr int total = 3 * RESN;
            transpose_lines_k<<<(total + 255) / 256, 256, 0, stream>>>(lines, lt);
        }
        {
            constexpr int total = NFEAT * CCTOT;
            transpose_w_k<<<(total + 255) / 256, 256, 0, stream>>>(W, wt);
        }
        if (ws_size >= NEED_SORT) {
            int*    hist  = (int*)((char*)d_ws + NEED_PLAIN);
            int*    start = (int*)((char*)d_ws + NEED_PLAIN + HIST_BYTES);
            float4* xyzs  = (float4*)((char*)d_ws + NEED_PLAIN + 2 * HIST_BYTES);
            zero_hist_k<<<(NBUCKET + 255) / 256, 256, 0, stream>>>(hist);
            hist_k<<<(NPTS + 255) / 256, 256, 0, stream>>>(xyz, hist);
            scan_k<<<1, 1024, 0, stream>>>(hist, start);
            scatter_k<<<(NPTS + 255) / 256, 256, 0, stream>>>(xyz, start, xyzs);
            tensor_vm_sorted_kernel<<<(NPTS + 255) / 256, 256, 0, stream>>>(
                xyzs, pt, lt, wt, out);
        } else {
            tensor_vm_kernel<<<(NPTS + 255) / 256, 256, 0, stream>>>(xyz, pt, lt, wt, out);
        }
    } else {
        tensor_vm_naive_kernel<<<(NPTS + 255) / 256, 256, 0, stream>>>(xyz, planes, lines, W, out);
    }
}